// Round 13
// baseline (138.117 us; speedup 1.0000x reference)
//
#include <hip/hip_runtime.h>

#define TB 4
#define TF 4096
#define DIN 1024
#define DK 128
#define M_TOT (TB * TF)  // 16384

typedef __attribute__((ext_vector_type(8))) short sh8;
typedef __attribute__((ext_vector_type(4))) float f32x4;

#if __has_builtin(__builtin_amdgcn_exp2f)
#define EXP2(x) __builtin_amdgcn_exp2f(x)
#else
#define EXP2(x) exp2f(x)
#endif

__device__ __forceinline__ unsigned short f2bf(float f) {
  unsigned int u = __builtin_bit_cast(unsigned int, f);
  u += 0x7FFFu + ((u >> 16) & 1u);
  return (unsigned short)(u >> 16);
}

__device__ __forceinline__ unsigned int pack_bf2(float a, float b) {
  return (unsigned int)f2bf(a) | ((unsigned int)f2bf(b) << 16);
}

__device__ __forceinline__ float bf2f(unsigned short u) {
  unsigned int x = ((unsigned int)u) << 16;
  return __builtin_bit_cast(float, x);
}

// Wf in MFMA-fragment order: Wf[((p*8 + t)*32 + ks)*512 + lane*8 + j]
//   = bf16(W_p[k = ks*32 + (lane>>4)*8 + j][col = t*16 + (lane&15)])
__global__ __launch_bounds__(256) void prep_wt_kernel(
    const float* __restrict__ Wq, const float* __restrict__ Wk,
    const float* __restrict__ Wv, unsigned short* __restrict__ Wf) {
  int idx = blockIdx.x * 256 + threadIdx.x;  // [0, 3*8*32*512)
  int j = idx & 7;
  int lane = (idx >> 3) & 63;
  int ks = (idx >> 9) & 31;
  int t = (idx >> 14) & 7;
  int p = idx >> 17;
  int col = t * 16 + (lane & 15);
  int k = ks * 32 + (lane >> 4) * 8 + j;
  const float* W = (p == 0) ? Wq : (p == 1) ? Wk : Wv;
  Wf[idx] = f2bf(W[k * DK + col]);
}

// Fused QKV projection. 512 threads = 8 waves; block = 64 rows of x.
// x tile staged in LDS as bf16 once per k-step. Wave w owns 16 cols for all
// 3 projections. Q pre-scaled by log2(e)/sqrt(128) (softmax in base-2).
// V stored transposed.
__global__ __launch_bounds__(512, 2) void proj_kernel(
    const float* __restrict__ x,            // [M_TOT][DIN]
    const unsigned short* __restrict__ Wf,  // fragment-ordered weights
    const float* __restrict__ bq, const float* __restrict__ bk,
    const float* __restrict__ bv,
    unsigned short* __restrict__ Qb,  // [M_TOT][DK] bf16 (pre-scaled)
    unsigned short* __restrict__ Kb,  // [M_TOT][DK] bf16
    unsigned short* __restrict__ VT)  // [TB][DK][TF] bf16
{
  const int tid = threadIdx.x;
  const int wave = tid >> 6;  // 0..7 = col tile
  const int lane = tid & 63;
  const int lr = lane & 15;
  const int lg = lane >> 4;
  const int m0 = blockIdx.x * 64;
  const int col = wave * 16 + lr;

  __shared__ unsigned short Xlds[64 * 32];  // x tile bf16 [row][k]

  f32x4 acc[3][4];
  const f32x4 z4 = {0.f, 0.f, 0.f, 0.f};
#pragma unroll
  for (int p = 0; p < 3; ++p)
#pragma unroll
    for (int m = 0; m < 4; ++m) acc[p][m] = z4;

  const int xr = tid >> 3;         // 0..63
  const int xk = (tid & 7) * 4;    // 0..28

  for (int k0 = 0; k0 < DIN; k0 += 32) {
    const float4 f = *(const float4*)(x + (size_t)(m0 + xr) * DIN + k0 + xk);
    ushort4 w4;
    w4.x = f2bf(f.x); w4.y = f2bf(f.y); w4.z = f2bf(f.z); w4.w = f2bf(f.w);
    __syncthreads();  // previous tile's reads complete
    *(ushort4*)&Xlds[xr * 32 + xk] = w4;
    __syncthreads();  // tile ready

    sh8 a[4];
#pragma unroll
    for (int m = 0; m < 4; ++m)
      a[m] = *(const sh8*)&Xlds[(m * 16 + lr) * 32 + lg * 8];
#pragma unroll
    for (int p = 0; p < 3; ++p) {
      sh8 b = *(const sh8*)(Wf + ((size_t)((p * 8 + wave) * 32 + (k0 >> 5))) *
                                     512 + lane * 8);
#pragma unroll
      for (int m = 0; m < 4; ++m)
        acc[p][m] =
            __builtin_amdgcn_mfma_f32_16x16x32_bf16(a[m], b, acc[p][m], 0, 0, 0);
    }
  }

  // log2(e)/sqrt(128): softmax computed base-2 downstream
  const float scale = 0.12751744f;
  const int b_idx = m0 >> 12;
  const float add_q = bq[col];
  const float add_k = bk[col];
  const float add_v = bv[col];
#pragma unroll
  for (int m = 0; m < 4; ++m) {
    const int rowbase = m0 + m * 16 + lg * 4;
#pragma unroll
    for (int r = 0; r < 4; ++r) {
      Qb[(size_t)(rowbase + r) * DK + col] =
          f2bf((acc[0][m][r] + add_q) * scale);
      Kb[(size_t)(rowbase + r) * DK + col] = f2bf(acc[1][m][r] + add_k);
    }
    const int fbase = (m0 & (TF - 1)) + m * 16 + lg * 4;
    ushort4 pv;
    pv.x = f2bf(acc[2][m][0] + add_v);
    pv.y = f2bf(acc[2][m][1] + add_v);
    pv.z = f2bf(acc[2][m][2] + add_v);
    pv.w = f2bf(acc[2][m][3] + add_v);
    *(ushort4*)(VT + ((size_t)b_idx * DK + col) * TF + fbase) = pv;
  }
}

// Flash attention, split-KV, async-STAGE split (T14): global loads for tile
// t+1 issue right after tile t is published (latency hides under compute);
// only the ds_write sits between barriers. 8 waves/block, QBLK=16/wave,
// swapped-operand QK^T, in-register P exchange, base-2 softmax + defer-max.
// Partials bf16. LDS = 17408 + 18432 = 35840 B.
template <int SPLIT>
__global__ __launch_bounds__(512, 2) void attn_part_kernel(
    const unsigned short* __restrict__ Qb, const unsigned short* __restrict__ Kb,
    const unsigned short* __restrict__ VT, unsigned short* __restrict__ Opart,
    float* __restrict__ Mpart, float* __restrict__ Lpart,
    float* __restrict__ out) {
  constexpr int CHUNK = TF / SPLIT;
  const int tid = threadIdx.x;
  const int lane = tid & 63;
  const int lr = lane & 15;
  const int lg = lane >> 4;

  // XCD swizzle: 2 XCDs per batch so K/V (2 MB bf16/batch) stays L2-resident.
  const int bid = blockIdx.x;  // grid = 128*SPLIT
  const int xcd = bid & 7;
  const int batch = xcd >> 1;
  const int idb = ((bid >> 3) << 1) | (xcd & 1);  // 0 .. 32*SPLIT-1
  const int slot = idb / SPLIT;                   // 0..31
  const int chunk = idb % SPLIT;
  const int wave = tid >> 6;  // 0..7
  const int q0 = batch * TF + slot * 128 + wave * 16;
  const int kbase = chunk * CHUNK;

  __shared__ unsigned short Klds[64 * 136];  // 64 kv rows x 128 d (pad->136)
  __shared__ unsigned short Vlds[128 * 72];  // 128 dv rows x 64 kv (pad->72)

  const unsigned short* Qp = Qb + (size_t)q0 * DK;
  const unsigned short* Kp = Kb + (size_t)batch * TF * DK;
  const unsigned short* Vp = VT + (size_t)batch * DK * TF;

  // staging lane geometry (512 threads, 2 x uint4 each for K and V)
  const int krow0 = tid >> 4, kc8 = tid & 15;       // +32 rows for i=1
  const int vrow0 = tid >> 3, vc8 = tid & 7;        // +64 rows for i=1

  uint4 kreg[2], vreg[2];

  sh8 aq[4];
#pragma unroll
  for (int dd = 0; dd < 4; ++dd)
    aq[dd] = *(const sh8*)(Qp + lr * DK + dd * 32 + lg * 8);

  const f32x4 z4 = {0.f, 0.f, 0.f, 0.f};
  f32x4 ot[8];  // ot[nb][r] = O^T[d = nb*16 + lg*4 + r][q = lr]
#pragma unroll
  for (int nb = 0; nb < 8; ++nb) ot[nb] = z4;
  float mrow = -1e30f, lrow = 0.f;  // m in log2 units

  const int srcA = lr + ((lane >> 4) & 1) * 32;  // holder lg' = 2*(lg&1)
  const int srcB = srcA + 16;                    // holder lg' = 2*(lg&1)+1
  const bool chi = (lg >= 2);                    // c = 2ks + (lg>>1)

  // prologue: stage first tile
#pragma unroll
  for (int i = 0; i < 2; ++i) {
    kreg[i] = *(const uint4*)(Kp + (size_t)(kbase + krow0 + i * 32) * DK +
                              kc8 * 8);
    vreg[i] =
        *(const uint4*)(Vp + (size_t)(vrow0 + i * 64) * TF + kbase + vc8 * 8);
  }
#pragma unroll
  for (int i = 0; i < 2; ++i) {
    *(uint4*)&Klds[(krow0 + i * 32) * 136 + kc8 * 8] = kreg[i];
    *(uint4*)&Vlds[(vrow0 + i * 64) * 72 + vc8 * 8] = vreg[i];
  }
  __syncthreads();

  for (int kk0 = kbase; kk0 < kbase + CHUNK; kk0 += 64) {
    const bool more = (kk0 + 64 < kbase + CHUNK);
    // issue next tile's global loads NOW; latency hides under compute below
    if (more) {
#pragma unroll
      for (int i = 0; i < 2; ++i) {
        kreg[i] = *(const uint4*)(Kp + (size_t)(kk0 + 64 + krow0 + i * 32) * DK +
                                  kc8 * 8);
        vreg[i] = *(const uint4*)(Vp + (size_t)(vrow0 + i * 64) * TF + kk0 + 64 +
                                  vc8 * 8);
      }
    }

    // S^T = K Q^T: st[c][r] = S[q=lr][kv = c*16 + lg*4 + r] (log2 units)
    f32x4 st[4];
#pragma unroll
    for (int c = 0; c < 4; ++c) st[c] = z4;
#pragma unroll
    for (int dd = 0; dd < 4; ++dd) {
#pragma unroll
      for (int c = 0; c < 4; ++c) {
        sh8 kb = *(const sh8*)&Klds[(c * 16 + lr) * 136 + dd * 32 + lg * 8];
        st[c] =
            __builtin_amdgcn_mfma_f32_16x16x32_bf16(kb, aq[dd], st[c], 0, 0, 0);
      }
    }

    // online softmax (base-2): lane owns q-row lr
    float mx = st[0][0];
#pragma unroll
    for (int c = 0; c < 4; ++c)
#pragma unroll
      for (int r = 0; r < 4; ++r) mx = fmaxf(mx, st[c][r]);
    mx = fmaxf(mx, __shfl_xor(mx, 16));
    mx = fmaxf(mx, __shfl_xor(mx, 32));

    // defer-max: skip rescale while tile max stays within THR of running max
    if (!__all(mx - mrow <= 11.5f)) {
      const float mnew = fmaxf(mrow, mx);
      const float al = EXP2(mrow - mnew);
      lrow *= al;
#pragma unroll
      for (int nb = 0; nb < 8; ++nb)
#pragma unroll
        for (int r = 0; r < 4; ++r) ot[nb][r] *= al;
      mrow = mnew;
    }

    float p[4][4];
    float rs = 0.f;
#pragma unroll
    for (int c = 0; c < 4; ++c)
#pragma unroll
      for (int r = 0; r < 4; ++r) {
        p[c][r] = EXP2(st[c][r] - mrow);
        rs += p[c][r];
      }
    rs += __shfl_xor(rs, 16);
    rs += __shfl_xor(rs, 32);
    lrow += rs;

    // pack P rows to bf16 pairs: up[c][h] = P[q=lr][kv=c*16+lg*4+2h+{0,1}]
    unsigned int up[4][2];
#pragma unroll
    for (int c = 0; c < 4; ++c) {
      up[c][0] = pack_bf2(p[c][0], p[c][1]);
      up[c][1] = pack_bf2(p[c][2], p[c][3]);
    }

    // O^T += V^T P^T; B-fragment built by cross-lane exchange:
    // lane (lr,lg) needs P[q=lr][kv=ks*32+lg*8+j], j=0..7.
#pragma unroll
    for (int ks = 0; ks < 2; ++ks) {
      unsigned int e0 = __shfl((int)up[2 * ks][0], srcA);
      unsigned int o0 = __shfl((int)up[2 * ks + 1][0], srcA);
      unsigned int e1 = __shfl((int)up[2 * ks][1], srcA);
      unsigned int o1 = __shfl((int)up[2 * ks + 1][1], srcA);
      unsigned int e2 = __shfl((int)up[2 * ks][0], srcB);
      unsigned int o2 = __shfl((int)up[2 * ks + 1][0], srcB);
      unsigned int e3 = __shfl((int)up[2 * ks][1], srcB);
      unsigned int o3 = __shfl((int)up[2 * ks + 1][1], srcB);
      union { unsigned int u[4]; sh8 v; } PA;
      PA.u[0] = chi ? o0 : e0;
      PA.u[1] = chi ? o1 : e1;
      PA.u[2] = chi ? o2 : e2;
      PA.u[3] = chi ? o3 : e3;
#pragma unroll
      for (int nb = 0; nb < 8; ++nb) {
        sh8 vb = *(const sh8*)&Vlds[(nb * 16 + lr) * 72 + ks * 32 + lg * 8];
        ot[nb] =
            __builtin_amdgcn_mfma_f32_16x16x32_bf16(vb, PA.v, ot[nb], 0, 0, 0);
      }
    }

    // publish next tile: only the LDS writes sit between barriers
    __syncthreads();  // all waves done reading tile t
    if (more) {
#pragma unroll
      for (int i = 0; i < 2; ++i) {
        *(uint4*)&Klds[(krow0 + i * 32) * 136 + kc8 * 8] = kreg[i];
        *(uint4*)&Vlds[(vrow0 + i * 64) * 72 + vc8 * 8] = vreg[i];
      }
      __syncthreads();  // tile t+1 ready
    }
  }

  if constexpr (SPLIT == 1) {
    const float inv = 1.0f / lrow;
#pragma unroll
    for (int nb = 0; nb < 8; ++nb) {
      float4 res = {ot[nb][0] * inv, ot[nb][1] * inv, ot[nb][2] * inv,
                    ot[nb][3] * inv};
      *(float4*)(out + (size_t)(q0 + lr) * DK + nb * 16 + lg * 4) = res;
    }
  } else {
    const int row = q0 + lr;
    if (lg == 0) {
      Mpart[(size_t)chunk * M_TOT + row] = mrow;  // log2 units
      Lpart[(size_t)chunk * M_TOT + row] = lrow;
    }
#pragma unroll
    for (int nb = 0; nb < 8; ++nb) {
      ushort4 res;
      res.x = f2bf(ot[nb][0]); res.y = f2bf(ot[nb][1]);
      res.z = f2bf(ot[nb][2]); res.w = f2bf(ot[nb][3]);
      *(ushort4*)(Opart + ((size_t)chunk * M_TOT + row) * DK + nb * 16 +
                  lg * 4) = res;
    }
  }
}

__global__ __launch_bounds__(256) void combine_kernel(
    const unsigned short* __restrict__ Opart, const float* __restrict__ Mpart,
    const float* __restrict__ Lpart, float* __restrict__ out, int split) {
  const int idx = blockIdx.x * 256 + threadIdx.x;  // M_TOT * 32
  const int row = idx >> 5;
  const int cq = (idx & 31) << 2;
  float m = -1e30f;
  for (int s = 0; s < split; ++s) m = fmaxf(m, Mpart[(size_t)s * M_TOT + row]);
  float den = 0.f;
  float4 acc = {0.f, 0.f, 0.f, 0.f};
  for (int s = 0; s < split; ++s) {
    const float w = EXP2(Mpart[(size_t)s * M_TOT + row] - m);  // log2 units
    den += w * Lpart[(size_t)s * M_TOT + row];
    const ushort4 v =
        *(const ushort4*)(Opart + ((size_t)s * M_TOT + row) * DK + cq);
    acc.x += w * bf2f(v.x); acc.y += w * bf2f(v.y);
    acc.z += w * bf2f(v.z); acc.w += w * bf2f(v.w);
  }
  const float inv = 1.0f / den;
  float4 res = {acc.x * inv, acc.y * inv, acc.z * inv, acc.w * inv};
  *(float4*)(out + (size_t)row * DK + cq) = res;
}

extern "C" void kernel_launch(void* const* d_in, const int* in_sizes, int n_in,
                              void* d_out, int out_size, void* d_ws,
                              size_t ws_size, hipStream_t stream) {
  const float* x = (const float*)d_in[0];
  const float* Wq = (const float*)d_in[1];
  const float* bq = (const float*)d_in[2];
  const float* Wk = (const float*)d_in[3];
  const float* bk = (const float*)d_in[4];
  const float* Wv = (const float*)d_in[5];
  const float* bv = (const float*)d_in[6];
  float* out = (float*)d_out;

  unsigned short* Wf = (unsigned short*)d_ws;              // 768 KB
  unsigned short* Qb = Wf + 3 * DK * DIN;                  // 4 MB
  unsigned short* Kb = Qb + (size_t)M_TOT * DK;            // 4 MB
  unsigned short* VT = Kb + (size_t)M_TOT * DK;            // 4 MB
  unsigned short* Opart = VT + (size_t)M_TOT * DK;         // split*4 MB (bf16)
  const size_t base_bytes = 2ull * (3 * DK * DIN + 3ull * M_TOT * DK);
  const size_t per_split = (size_t)M_TOT * DK * 2 + 2ull * M_TOT * 4;

  prep_wt_kernel<<<(3 * DK * DIN) / 256, 256, 0, stream>>>(Wq, Wk, Wv, Wf);
  proj_kernel<<<M_TOT / 64, 512, 0, stream>>>(x, Wf, bq, bk, bv, Qb, Kb, VT);

  int split;
  if (ws_size >= base_bytes + 4 * per_split) split = 4;
  else if (ws_size >= base_bytes + 2 * per_split) split = 2;
  else split = 1;

  float* Mpart = (float*)(Opart + (size_t)split * M_TOT * DK);
  float* Lpart = Mpart + (size_t)split * M_TOT;

  if (split == 4) {
    attn_part_kernel<4><<<128 * 4, 512, 0, stream>>>(Qb, Kb, VT, Opart, Mpart,
                                                     Lpart, out);
    combine_kernel<<<M_TOT * 32 / 256, 256, 0, stream>>>(Opart, Mpart, Lpart,
                                                         out, 4);
  } else if (split == 2) {
    attn_part_kernel<2><<<128 * 2, 512, 0, stream>>>(Qb, Kb, VT, Opart, Mpart,
                                                     Lpart, out);
    combine_kernel<<<M_TOT * 32 / 256, 256, 0, stream>>>(Opart, Mpart, Lpart,
                                                         out, 2);
  } else {
    attn_part_kernel<1><<<128, 512, 0, stream>>>(Qb, Kb, VT, nullptr, nullptr,
                                                 nullptr, out);
  }
}

// Round 14
// 104.561 us; speedup vs baseline: 1.3209x; 1.3209x over previous
//
#include <hip/hip_runtime.h>

#define TB 4
#define TF 4096
#define DIN 1024
#define DK 128
#define M_TOT (TB * TF)  // 16384

typedef __attribute__((ext_vector_type(8))) short sh8;
typedef __attribute__((ext_vector_type(4))) float f32x4;

#if __has_builtin(__builtin_amdgcn_exp2f)
#define EXP2(x) __builtin_amdgcn_exp2f(x)
#else
#define EXP2(x) exp2f(x)
#endif

__device__ __forceinline__ unsigned short f2bf(float f) {
  unsigned int u = __builtin_bit_cast(unsigned int, f);
  u += 0x7FFFu + ((u >> 16) & 1u);
  return (unsigned short)(u >> 16);
}

__device__ __forceinline__ unsigned int pack_bf2(float a, float b) {
  return (unsigned int)f2bf(a) | ((unsigned int)f2bf(b) << 16);
}

__device__ __forceinline__ float bf2f(unsigned short u) {
  unsigned int x = ((unsigned int)u) << 16;
  return __builtin_bit_cast(float, x);
}

// Wf in MFMA-fragment order: Wf[((p*8 + t)*32 + ks)*512 + lane*8 + j]
//   = bf16(W_p[k = ks*32 + (lane>>4)*8 + j][col = t*16 + (lane&15)])
__global__ __launch_bounds__(256) void prep_wt_kernel(
    const float* __restrict__ Wq, const float* __restrict__ Wk,
    const float* __restrict__ Wv, unsigned short* __restrict__ Wf) {
  int idx = blockIdx.x * 256 + threadIdx.x;  // [0, 3*8*32*512)
  int j = idx & 7;
  int lane = (idx >> 3) & 63;
  int ks = (idx >> 9) & 31;
  int t = (idx >> 14) & 7;
  int p = idx >> 17;
  int col = t * 16 + (lane & 15);
  int k = ks * 32 + (lane >> 4) * 8 + j;
  const float* W = (p == 0) ? Wq : (p == 1) ? Wk : Wv;
  Wf[idx] = f2bf(W[k * DK + col]);
}

// Fused QKV projection. 512 threads = 8 waves; block = 64 rows of x.
// BK=64: x tile (64x64 bf16, padded rows 64->68) staged per iteration ->
// 16 iterations x 2 barriers (was 32x2). Wave w owns 16 cols for all 3
// projections. Q pre-scaled by log2(e)/sqrt(128). V stored transposed.
__global__ __launch_bounds__(512, 2) void proj_kernel(
    const float* __restrict__ x,            // [M_TOT][DIN]
    const unsigned short* __restrict__ Wf,  // fragment-ordered weights
    const float* __restrict__ bq, const float* __restrict__ bk,
    const float* __restrict__ bv,
    unsigned short* __restrict__ Qb,  // [M_TOT][DK] bf16 (pre-scaled)
    unsigned short* __restrict__ Kb,  // [M_TOT][DK] bf16
    unsigned short* __restrict__ VT)  // [TB][DK][TF] bf16
{
  const int tid = threadIdx.x;
  const int wave = tid >> 6;  // 0..7 = col tile
  const int lane = tid & 63;
  const int lr = lane & 15;
  const int lg = lane >> 4;
  const int m0 = blockIdx.x * 64;
  const int col = wave * 16 + lr;

  __shared__ unsigned short Xlds[64 * 68];  // x tile bf16 [row][k], pad 64->68

  f32x4 acc[3][4];
  const f32x4 z4 = {0.f, 0.f, 0.f, 0.f};
#pragma unroll
  for (int p = 0; p < 3; ++p)
#pragma unroll
    for (int m = 0; m < 4; ++m) acc[p][m] = z4;

  const int xr = tid >> 3;        // 0..63
  const int xk8 = (tid & 7) * 8;  // 0..56

  for (int k0 = 0; k0 < DIN; k0 += 64) {
    const float* xp = x + (size_t)(m0 + xr) * DIN + k0 + xk8;
    const float4 f0 = *(const float4*)xp;
    const float4 f1 = *(const float4*)(xp + 4);
    union { sh8 v; unsigned short u[8]; } U;
    U.u[0] = f2bf(f0.x); U.u[1] = f2bf(f0.y);
    U.u[2] = f2bf(f0.z); U.u[3] = f2bf(f0.w);
    U.u[4] = f2bf(f1.x); U.u[5] = f2bf(f1.y);
    U.u[6] = f2bf(f1.z); U.u[7] = f2bf(f1.w);
    __syncthreads();  // previous tile's reads complete
    *(sh8*)&Xlds[xr * 68 + xk8] = U.v;
    __syncthreads();  // tile ready

    sh8 a[4][2];
#pragma unroll
    for (int m = 0; m < 4; ++m)
#pragma unroll
      for (int s = 0; s < 2; ++s)
        a[m][s] = *(const sh8*)&Xlds[(m * 16 + lr) * 68 + s * 32 + lg * 8];
#pragma unroll
    for (int p = 0; p < 3; ++p) {
#pragma unroll
      for (int s = 0; s < 2; ++s) {
        sh8 b = *(const sh8*)(Wf +
                              ((size_t)((p * 8 + wave) * 32 + (k0 >> 5) + s)) *
                                  512 +
                              lane * 8);
#pragma unroll
        for (int m = 0; m < 4; ++m)
          acc[p][m] = __builtin_amdgcn_mfma_f32_16x16x32_bf16(a[m][s], b,
                                                              acc[p][m], 0, 0,
                                                              0);
      }
    }
  }

  // log2(e)/sqrt(128): softmax computed base-2 downstream
  const float scale = 0.12751744f;
  const int b_idx = m0 >> 12;
  const float add_q = bq[col];
  const float add_k = bk[col];
  const float add_v = bv[col];
#pragma unroll
  for (int m = 0; m < 4; ++m) {
    const int rowbase = m0 + m * 16 + lg * 4;
#pragma unroll
    for (int r = 0; r < 4; ++r) {
      Qb[(size_t)(rowbase + r) * DK + col] =
          f2bf((acc[0][m][r] + add_q) * scale);
      Kb[(size_t)(rowbase + r) * DK + col] = f2bf(acc[1][m][r] + add_k);
    }
    const int fbase = (m0 & (TF - 1)) + m * 16 + lg * 4;
    ushort4 pv;
    pv.x = f2bf(acc[2][m][0] + add_v);
    pv.y = f2bf(acc[2][m][1] + add_v);
    pv.z = f2bf(acc[2][m][2] + add_v);
    pv.w = f2bf(acc[2][m][3] + add_v);
    *(ushort4*)(VT + ((size_t)b_idx * DK + col) * TF + fbase) = pv;
  }
}

// Flash attention, split-KV. 8 waves/block = 128 q rows; QBLK=16/wave
// (R9-proven body, 48 VGPR, launch_bounds(512,2)). SPLIT=4 (best measured;
// SPLIT=8 added combine cost for no attn gain; T14 reg-staging spilled).
template <int SPLIT>
__global__ __launch_bounds__(512, 2) void attn_part_kernel(
    const unsigned short* __restrict__ Qb, const unsigned short* __restrict__ Kb,
    const unsigned short* __restrict__ VT, unsigned short* __restrict__ Opart,
    float* __restrict__ Mpart, float* __restrict__ Lpart,
    float* __restrict__ out) {
  constexpr int CHUNK = TF / SPLIT;
  const int tid = threadIdx.x;
  const int lane = tid & 63;
  const int lr = lane & 15;
  const int lg = lane >> 4;

  // XCD swizzle: 2 XCDs per batch so K/V (2 MB bf16/batch) stays L2-resident.
  const int bid = blockIdx.x;  // grid = 128*SPLIT
  const int xcd = bid & 7;
  const int batch = xcd >> 1;
  const int idb = ((bid >> 3) << 1) | (xcd & 1);  // 0 .. 32*SPLIT-1
  const int slot = idb / SPLIT;                   // 0..31
  const int chunk = idb % SPLIT;
  const int wave = tid >> 6;  // 0..7
  const int q0 = batch * TF + slot * 128 + wave * 16;
  const int kbase = chunk * CHUNK;

  __shared__ unsigned short Klds[64 * 136];  // 64 kv rows x 128 d (pad->136)
  __shared__ unsigned short Vlds[128 * 72];  // 128 dv rows x 64 kv (pad->72)

  const unsigned short* Qp = Qb + (size_t)q0 * DK;
  const unsigned short* Kp = Kb + (size_t)batch * TF * DK;
  const unsigned short* Vp = VT + (size_t)batch * DK * TF;

  sh8 aq[4];
#pragma unroll
  for (int dd = 0; dd < 4; ++dd)
    aq[dd] = *(const sh8*)(Qp + lr * DK + dd * 32 + lg * 8);

  const f32x4 z4 = {0.f, 0.f, 0.f, 0.f};
  f32x4 ot[8];  // ot[nb][r] = O^T[d = nb*16 + lg*4 + r][q = lr]
#pragma unroll
  for (int nb = 0; nb < 8; ++nb) ot[nb] = z4;
  float mrow = -1e30f, lrow = 0.f;  // m in log2 units

  const int srcA = lr + ((lane >> 4) & 1) * 32;  // holder lg' = 2*(lg&1)
  const int srcB = srcA + 16;                    // holder lg' = 2*(lg&1)+1
  const bool chi = (lg >= 2);                    // c = 2ks + (lg>>1)

  for (int kk0 = kbase; kk0 < kbase + CHUNK; kk0 += 64) {
    __syncthreads();
#pragma unroll
    for (int i = 0; i < 2; ++i) {  // stage K tile 64x128 (512 threads)
      int c = tid + i * 512;
      int row = c >> 4, c8 = c & 15;
      *(uint4*)&Klds[row * 136 + c8 * 8] =
          *(const uint4*)(Kp + (size_t)(kk0 + row) * DK + c8 * 8);
    }
#pragma unroll
    for (int i = 0; i < 2; ++i) {  // stage V^T tile 128x64
      int c = tid + i * 512;
      int row = c >> 3, c8 = c & 7;
      *(uint4*)&Vlds[row * 72 + c8 * 8] =
          *(const uint4*)(Vp + (size_t)row * TF + kk0 + c8 * 8);
    }
    __syncthreads();

    // S^T = K Q^T: st[c][r] = S[q=lr][kv = c*16 + lg*4 + r] (log2 units)
    f32x4 st[4];
#pragma unroll
    for (int c = 0; c < 4; ++c) st[c] = z4;
#pragma unroll
    for (int dd = 0; dd < 4; ++dd) {
#pragma unroll
      for (int c = 0; c < 4; ++c) {
        sh8 kb = *(const sh8*)&Klds[(c * 16 + lr) * 136 + dd * 32 + lg * 8];
        st[c] =
            __builtin_amdgcn_mfma_f32_16x16x32_bf16(kb, aq[dd], st[c], 0, 0, 0);
      }
    }

    // online softmax (base-2): lane owns q-row lr
    float mx = st[0][0];
#pragma unroll
    for (int c = 0; c < 4; ++c)
#pragma unroll
      for (int r = 0; r < 4; ++r) mx = fmaxf(mx, st[c][r]);
    mx = fmaxf(mx, __shfl_xor(mx, 16));
    mx = fmaxf(mx, __shfl_xor(mx, 32));

    // defer-max: skip rescale while tile max stays within THR of running max
    if (!__all(mx - mrow <= 11.5f)) {
      const float mnew = fmaxf(mrow, mx);
      const float al = EXP2(mrow - mnew);
      lrow *= al;
#pragma unroll
      for (int nb = 0; nb < 8; ++nb)
#pragma unroll
        for (int r = 0; r < 4; ++r) ot[nb][r] *= al;
      mrow = mnew;
    }

    float p[4][4];
    float rs = 0.f;
#pragma unroll
    for (int c = 0; c < 4; ++c)
#pragma unroll
      for (int r = 0; r < 4; ++r) {
        p[c][r] = EXP2(st[c][r] - mrow);
        rs += p[c][r];
      }
    rs += __shfl_xor(rs, 16);
    rs += __shfl_xor(rs, 32);
    lrow += rs;

    // pack P rows to bf16 pairs: up[c][h] = P[q=lr][kv=c*16+lg*4+2h+{0,1}]
    unsigned int up[4][2];
#pragma unroll
    for (int c = 0; c < 4; ++c) {
      up[c][0] = pack_bf2(p[c][0], p[c][1]);
      up[c][1] = pack_bf2(p[c][2], p[c][3]);
    }

    // O^T += V^T P^T; B-fragment built by cross-lane exchange:
    // lane (lr,lg) needs P[q=lr][kv=ks*32+lg*8+j], j=0..7.
#pragma unroll
    for (int ks = 0; ks < 2; ++ks) {
      unsigned int e0 = __shfl((int)up[2 * ks][0], srcA);
      unsigned int o0 = __shfl((int)up[2 * ks + 1][0], srcA);
      unsigned int e1 = __shfl((int)up[2 * ks][1], srcA);
      unsigned int o1 = __shfl((int)up[2 * ks + 1][1], srcA);
      unsigned int e2 = __shfl((int)up[2 * ks][0], srcB);
      unsigned int o2 = __shfl((int)up[2 * ks + 1][0], srcB);
      unsigned int e3 = __shfl((int)up[2 * ks][1], srcB);
      unsigned int o3 = __shfl((int)up[2 * ks + 1][1], srcB);
      union { unsigned int u[4]; sh8 v; } PA;
      PA.u[0] = chi ? o0 : e0;
      PA.u[1] = chi ? o1 : e1;
      PA.u[2] = chi ? o2 : e2;
      PA.u[3] = chi ? o3 : e3;
#pragma unroll
      for (int nb = 0; nb < 8; ++nb) {
        sh8 vb = *(const sh8*)&Vlds[(nb * 16 + lr) * 72 + ks * 32 + lg * 8];
        ot[nb] =
            __builtin_amdgcn_mfma_f32_16x16x32_bf16(vb, PA.v, ot[nb], 0, 0, 0);
      }
    }
  }

  if constexpr (SPLIT == 1) {
    const float inv = 1.0f / lrow;
#pragma unroll
    for (int nb = 0; nb < 8; ++nb) {
      float4 res = {ot[nb][0] * inv, ot[nb][1] * inv, ot[nb][2] * inv,
                    ot[nb][3] * inv};
      *(float4*)(out + (size_t)(q0 + lr) * DK + nb * 16 + lg * 4) = res;
    }
  } else {
    const int row = q0 + lr;
    if (lg == 0) {
      Mpart[(size_t)chunk * M_TOT + row] = mrow;  // log2 units
      Lpart[(size_t)chunk * M_TOT + row] = lrow;
    }
#pragma unroll
    for (int nb = 0; nb < 8; ++nb) {
      ushort4 res;
      res.x = f2bf(ot[nb][0]); res.y = f2bf(ot[nb][1]);
      res.z = f2bf(ot[nb][2]); res.w = f2bf(ot[nb][3]);
      *(ushort4*)(Opart + ((size_t)chunk * M_TOT + row) * DK + nb * 16 +
                  lg * 4) = res;
    }
  }
}

__global__ __launch_bounds__(256) void combine_kernel(
    const unsigned short* __restrict__ Opart, const float* __restrict__ Mpart,
    const float* __restrict__ Lpart, float* __restrict__ out, int split) {
  const int idx = blockIdx.x * 256 + threadIdx.x;  // M_TOT * 32
  const int row = idx >> 5;
  const int cq = (idx & 31) << 2;
  float m = -1e30f;
  for (int s = 0; s < split; ++s) m = fmaxf(m, Mpart[(size_t)s * M_TOT + row]);
  float den = 0.f;
  float4 acc = {0.f, 0.f, 0.f, 0.f};
  for (int s = 0; s < split; ++s) {
    const float w = EXP2(Mpart[(size_t)s * M_TOT + row] - m);  // log2 units
    den += w * Lpart[(size_t)s * M_TOT + row];
    const ushort4 v =
        *(const ushort4*)(Opart + ((size_t)s * M_TOT + row) * DK + cq);
    acc.x += w * bf2f(v.x); acc.y += w * bf2f(v.y);
    acc.z += w * bf2f(v.z); acc.w += w * bf2f(v.w);
  }
  const float inv = 1.0f / den;
  float4 res = {acc.x * inv, acc.y * inv, acc.z * inv, acc.w * inv};
  *(float4*)(out + (size_t)row * DK + cq) = res;
}

extern "C" void kernel_launch(void* const* d_in, const int* in_sizes, int n_in,
                              void* d_out, int out_size, void* d_ws,
                              size_t ws_size, hipStream_t stream) {
  const float* x = (const float*)d_in[0];
  const float* Wq = (const float*)d_in[1];
  const float* bq = (const float*)d_in[2];
  const float* Wk = (const float*)d_in[3];
  const float* bk = (const float*)d_in[4];
  const float* Wv = (const float*)d_in[5];
  const float* bv = (const float*)d_in[6];
  float* out = (float*)d_out;

  unsigned short* Wf = (unsigned short*)d_ws;              // 768 KB
  unsigned short* Qb = Wf + 3 * DK * DIN;                  // 4 MB
  unsigned short* Kb = Qb + (size_t)M_TOT * DK;            // 4 MB
  unsigned short* VT = Kb + (size_t)M_TOT * DK;            // 4 MB
  unsigned short* Opart = VT + (size_t)M_TOT * DK;         // split*4 MB (bf16)
  const size_t base_bytes = 2ull * (3 * DK * DIN + 3ull * M_TOT * DK);
  const size_t per_split = (size_t)M_TOT * DK * 2 + 2ull * M_TOT * 4;

  prep_wt_kernel<<<(3 * DK * DIN) / 256, 256, 0, stream>>>(Wq, Wk, Wv, Wf);
  proj_kernel<<<M_TOT / 64, 512, 0, stream>>>(x, Wf, bq, bk, bv, Qb, Kb, VT);

  int split;
  if (ws_size >= base_bytes + 4 * per_split) split = 4;
  else if (ws_size >= base_bytes + 2 * per_split) split = 2;
  else split = 1;

  float* Mpart = (float*)(Opart + (size_t)split * M_TOT * DK);
  float* Lpart = Mpart + (size_t)split * M_TOT;

  if (split == 4) {
    attn_part_kernel<4><<<128 * 4, 512, 0, stream>>>(Qb, Kb, VT, Opart, Mpart,
                                                     Lpart, out);
    combine_kernel<<<M_TOT * 32 / 256, 256, 0, stream>>>(Opart, Mpart, Lpart,
                                                         out, 4);
  } else if (split == 2) {
    attn_part_kernel<2><<<128 * 2, 512, 0, stream>>>(Qb, Kb, VT, Opart, Mpart,
                                                     Lpart, out);
    combine_kernel<<<M_TOT * 32 / 256, 256, 0, stream>>>(Opart, Mpart, Lpart,
                                                         out, 2);
  } else {
    attn_part_kernel<1><<<128, 512, 0, stream>>>(Qb, Kb, VT, nullptr, nullptr,
                                                 nullptr, out);
  }
}